// Round 6
// baseline (1015.560 us; speedup 1.0000x reference)
//
#include <hip/hip_runtime.h>

// ---------------------------------------------------------------------------
// AttnBlock: LN(channel) -> QKV 1x1 conv -> full attention (L=4096, d=512)
//            -> proj -> SELU -> residual.   B=4, C=512, L=4096.  bf16 MFMA.
// Round 6: flash KVBLK=64 (one barrier per 64 kv, 32 iters), V direct from
// L2 (no VTs LDS), Ps XOR-swizzled, region order QKT -> SM -> PV(t-1) to
// keep arch VGPR <= 128. LDS = 128KB K-dbuf + 32KB Ps-dbuf = 160KB.
// ---------------------------------------------------------------------------

typedef __attribute__((ext_vector_type(8))) __bf16 bf16x8;
typedef __attribute__((ext_vector_type(4))) __bf16 bf16x4;
typedef __attribute__((ext_vector_type(4))) float  f32x4;

__device__ __forceinline__ f32x4 mfma16(bf16x8 a, bf16x8 b, f32x4 c) {
  return __builtin_amdgcn_mfma_f32_16x16x32_bf16(a, b, c, 0, 0, 0);
}

// async global->LDS, 16B per lane; lds dest is wave-uniform base (HW adds lane*16)
__device__ __forceinline__ void gll16(const void* g, void* l) {
  __builtin_amdgcn_global_load_lds(
      (const __attribute__((address_space(1))) unsigned int*)g,
      (__attribute__((address_space(3))) unsigned int*)l, 16, 0, 0);
}

__device__ __forceinline__ float selu_f(float v) {
  return 1.0507009873554805f * (v > 0.f ? v : 1.6732632423543772f * (__expf(v) - 1.f));
}

// log2(e) / sqrt(512): folded into q at the QKV-GEMM epilogue
#define QSCALE ((float)(1.4426950408889634 / 22.627416997969522))

// ---------------------------------------------------------------------------
// weight fp32 -> bf16, 4 matrices packed contiguously [wq;wk;wv;wp]
// ---------------------------------------------------------------------------
__global__ __launch_bounds__(256) void cvt_w(const float* __restrict__ w0,
                                             const float* __restrict__ w1,
                                             const float* __restrict__ w2,
                                             const float* __restrict__ w3,
                                             __bf16* __restrict__ dst) {
  int idx = blockIdx.x * 256 + threadIdx.x;           // 0..262143 (x4 floats)
  int which = idx >> 16;
  const float* s = which == 0 ? w0 : which == 1 ? w1 : which == 2 ? w2 : w3;
  f32x4 v = *(const f32x4*)(s + (size_t)(idx & 65535) * 4);
  bf16x4 o = {(__bf16)v.x, (__bf16)v.y, (__bf16)v.z, (__bf16)v.w};
  *(bf16x4*)(dst + (size_t)idx * 4) = o;
}

// ---------------------------------------------------------------------------
// LayerNorm stats over C for each (b,l): coalesced along l
// ---------------------------------------------------------------------------
__global__ __launch_bounds__(256) void ln_stats(const float* __restrict__ x,
                                                float* __restrict__ mu,
                                                float* __restrict__ rs) {
  __shared__ float shs[4][64], shq[4][64];
  int b = blockIdx.y, l0 = blockIdx.x * 64;
  int i = threadIdx.x & 63, j = threadIdx.x >> 6;
  const float* xp = x + (size_t)b * 512 * 4096 + l0 + i;
  float s = 0.f, sq = 0.f;
  for (int c = j; c < 512; c += 4) {
    float v = xp[(size_t)c * 4096];
    s += v; sq += v * v;
  }
  shs[j][i] = s; shq[j][i] = sq;
  __syncthreads();
  if (threadIdx.x < 64) {
    float S = shs[0][i] + shs[1][i] + shs[2][i] + shs[3][i];
    float Q = shq[0][i] + shq[1][i] + shq[2][i] + shq[3][i];
    float m = S * (1.f / 512.f);
    float var = Q * (1.f / 512.f) - m * m;
    int idx = b * 4096 + l0 + i;
    mu[idx] = m;
    rs[idx] = rsqrtf(var + 1e-5f);
  }
}

// ---------------------------------------------------------------------------
// LN apply + transpose: x[b,c,l] -> h[(b*L+l)][c] bf16, both sides coalesced
// ---------------------------------------------------------------------------
__global__ __launch_bounds__(256) void ln_apply(const float* __restrict__ x,
                                                const float* __restrict__ mu,
                                                const float* __restrict__ rs,
                                                const float* __restrict__ lw,
                                                const float* __restrict__ lb,
                                                __bf16* __restrict__ h) {
  __shared__ float t[64][65];
  int b = blockIdx.z, c0 = blockIdx.y * 64, l0 = blockIdx.x * 64;
  int li = threadIdx.x & 63, r4 = threadIdx.x >> 6;
  const float* xp = x + (size_t)(b * 512 + c0) * 4096 + l0;
#pragma unroll
  for (int rr = 0; rr < 16; ++rr) {
    int cl = rr * 4 + r4;
    t[cl][li] = xp[(size_t)cl * 4096 + li];
  }
  __syncthreads();
  float gw = lw[c0 + li], gb = lb[c0 + li];
#pragma unroll
  for (int rr = 0; rr < 16; ++rr) {
    int lr = rr * 4 + r4;
    int l = l0 + lr;
    float m = mu[b * 4096 + l], r = rs[b * 4096 + l];
    float v = (t[li][lr] - m) * r * gw + gb;
    h[((size_t)b * 4096 + l) * 512 + c0 + li] = (__bf16)v;
  }
}

// ---------------------------------------------------------------------------
// 128x128 bf16 GEMM, C[i][j] = sum_k A[i][k]*W[j][k], K=512, BK=64.
// QKV variant: q scaled by QSCALE; q,k row-major [pos][c]; v transposed
// to vt[b][c][l].  1-D grid, XCD-chunked: m-panels pinned to one XCD.
// ---------------------------------------------------------------------------
__global__ __launch_bounds__(256, 2) void gemm_qkv(
    const __bf16* __restrict__ A, const __bf16* __restrict__ W,
    const float* __restrict__ b0, const float* __restrict__ b1,
    const float* __restrict__ b2, __bf16* __restrict__ out,
    __bf16* __restrict__ vt) {
  __shared__ __align__(16) __bf16 As[128 * 64];
  __shared__ __align__(16) __bf16 Bs[128 * 64];
  const int tid = threadIdx.x;
  const int w = tid >> 6, lane = tid & 63, g = lane >> 4, li = lane & 15;
  // 1536 blocks: xcd = id&7 owns m-tiles [16*xcd, 16*xcd+16) x all 12 n-tiles
  const int id = blockIdx.x;
  const int jj = id >> 3;
  const int m0 = (16 * (id & 7) + jj / 12) * 128;
  const int n0 = (jj % 12) * 128;
  const int wm = w >> 1, wn = w & 1;
  const int srow = lane >> 3;                  // 0..7
  const int scol = ((lane & 7) ^ srow) * 8;    // swizzled source granule (elems)
  f32x4 acc[4][4] = {};
  for (int kt = 0; kt < 8; ++kt) {
    __syncthreads();
#pragma unroll
    for (int qq = 0; qq < 4; ++qq) {
      int r = w * 32 + qq * 8;
      gll16(A + (size_t)(m0 + r + srow) * 512 + kt * 64 + scol, &As[r * 64]);
      gll16(W + (size_t)(n0 + r + srow) * 512 + kt * 64 + scol, &Bs[r * 64]);
    }
    __syncthreads();
#pragma unroll
    for (int kk = 0; kk < 2; ++kk) {
      bf16x8 af[4], bf[4];
#pragma unroll
      for (int t = 0; t < 4; ++t) {
        int ra = wm * 64 + t * 16 + li;
        af[t] = *(const bf16x8*)&As[ra * 64 + ((kk * 32 + 8 * g) ^ ((ra & 7) * 8))];
        int rb = wn * 64 + t * 16 + li;
        bf[t] = *(const bf16x8*)&Bs[rb * 64 + ((kk * 32 + 8 * g) ^ ((rb & 7) * 8))];
      }
#pragma unroll
      for (int i = 0; i < 4; ++i)
#pragma unroll
        for (int j = 0; j < 4; ++j) acc[i][j] = mfma16(af[i], bf[j], acc[i][j]);
    }
  }
  const int which = n0 >> 9;  // 0=q,1=k,2=v (block never crosses a 512 boundary)
  if (which < 2) {
    const float* bb = which == 0 ? b0 : b1;
    const float sc = which == 0 ? QSCALE : 1.0f;
    __bf16* o = out + (size_t)which * 8388608;
#pragma unroll
    for (int i = 0; i < 4; ++i) {
#pragma unroll
      for (int j = 0; j < 4; ++j) {
        int r = m0 + wm * 64 + i * 16 + 4 * g;
        int c = (n0 & 511) + wn * 64 + j * 16 + li;
        float bv = bb[c];
#pragma unroll
        for (int e = 0; e < 4; ++e)
          o[(size_t)(r + e) * 512 + c] = (__bf16)((acc[i][j][e] + bv) * sc);
      }
    }
  } else {
    // transposed write: vt[b][channel][l]
#pragma unroll
    for (int i = 0; i < 4; ++i) {
#pragma unroll
      for (int j = 0; j < 4; ++j) {
        int r = m0 + wm * 64 + i * 16 + 4 * g;   // flat position b*4096+l
        int c = (n0 & 511) + wn * 64 + j * 16 + li;  // channel
        float bv = b2[c];
#pragma unroll
        for (int e = 0; e < 4; ++e) {
          int row = r + e;
          vt[((size_t)(row >> 12) * 512 + c) * 4096 + (row & 4095)] =
              (__bf16)(acc[i][j][e] + bv);
        }
      }
    }
  }
}

// PP variant: C[o][pos] = sum wp[o][k]*ao[pos][k]; epilogue bias+SELU+residual,
// writes out[b][o][l] fp32 fully coalesced (lanes along l).
__global__ __launch_bounds__(256, 2) void gemm_pp(
    const __bf16* __restrict__ A, const __bf16* __restrict__ Bm,
    const float* __restrict__ bias, const float* __restrict__ xres,
    float* __restrict__ out) {
  __shared__ __align__(16) __bf16 As[128 * 64];
  __shared__ __align__(16) __bf16 Bs[128 * 64];
  const int tid = threadIdx.x;
  const int w = tid >> 6, lane = tid & 63, g = lane >> 4, li = lane & 15;
  // 512 blocks: xcd = id&7 owns position-tiles [16*xcd,16*xcd+16) x 4 m-tiles
  const int id = blockIdx.x;
  const int jj = id >> 3;
  const int n0 = (16 * (id & 7) + (jj & 15)) * 128;  // position
  const int m0 = (jj >> 4) * 128;                    // output channel
  const int wm = w >> 1, wn = w & 1;
  const int srow = lane >> 3;
  const int scol = ((lane & 7) ^ srow) * 8;
  f32x4 acc[4][4] = {};
  for (int kt = 0; kt < 8; ++kt) {
    __syncthreads();
#pragma unroll
    for (int qq = 0; qq < 4; ++qq) {
      int r = w * 32 + qq * 8;
      gll16(A + (size_t)(m0 + r + srow) * 512 + kt * 64 + scol, &As[r * 64]);
      gll16(Bm + (size_t)(n0 + r + srow) * 512 + kt * 64 + scol, &Bs[r * 64]);
    }
    __syncthreads();
#pragma unroll
    for (int kk = 0; kk < 2; ++kk) {
      bf16x8 af[4], bf[4];
#pragma unroll
      for (int t = 0; t < 4; ++t) {
        int ra = wm * 64 + t * 16 + li;
        af[t] = *(const bf16x8*)&As[ra * 64 + ((kk * 32 + 8 * g) ^ ((ra & 7) * 8))];
        int rb = wn * 64 + t * 16 + li;
        bf[t] = *(const bf16x8*)&Bs[rb * 64 + ((kk * 32 + 8 * g) ^ ((rb & 7) * 8))];
      }
#pragma unroll
      for (int i = 0; i < 4; ++i)
#pragma unroll
        for (int j = 0; j < 4; ++j) acc[i][j] = mfma16(af[i], bf[j], acc[i][j]);
    }
  }
#pragma unroll
  for (int i = 0; i < 4; ++i) {
#pragma unroll
    for (int j = 0; j < 4; ++j) {
      int r = m0 + wm * 64 + i * 16 + 4 * g;   // output channel o
      int c = n0 + wn * 64 + j * 16 + li;      // flat position b*4096+l
      int bb = c >> 12, l = c & 4095;
#pragma unroll
      for (int e = 0; e < 4; ++e) {
        float v = acc[i][j][e] + bias[r + e];
        size_t oi = ((size_t)bb * 512 + (r + e)) * 4096 + l;
        out[oi] = xres[oi] + selu_f(v);
      }
    }
  }
}

// ---------------------------------------------------------------------------
// Flash attention, one block = 128 q-rows x one half (2048) of the KV range.
// Grid 256 blocks: group = id&7 = b*2+half pinned per-XCD (K/V L2-resident).
// 8 waves: wave w owns S rows 16w..16w+15 and O cols 64w..64w+63.
// KVBLK=64, 32 iterations, ONE barrier each.
// K:  LDS [2][64][512] (128KB), XOR-swizzled via pre-swizzled gll source.
// Ps: LDS [2][128][64] (32KB), 8-granule XOR swizzle (gcol = (kv>>3)^(row&7)).
// V:  direct from global vt[b][c][l] (L2-resident via XCD grouping).
// Region: QKT(t) -> softmax(t)->Ps[cur] -> PV(t-1) -> barrier.
// Softmax: no max-shift (exp2 of pre-scaled scores); l via ones-MFMA;
// O unnormalized, normalized in combine2.
// ---------------------------------------------------------------------------
__global__ __launch_bounds__(512, 2) void flash_half(
    const __bf16* __restrict__ Q, const __bf16* __restrict__ K,
    const __bf16* __restrict__ VT, __bf16* __restrict__ Op,
    float* __restrict__ stats) {
  __shared__ __align__(16) __bf16 Ks[2][64][512];   // 128 KB
  __shared__ __align__(16) __bf16 Ps[2][128][64];   // 32 KB

  const int tid = threadIdx.x;
  const int w = tid >> 6, lane = tid & 63, g = lane >> 4, li = lane & 15;
  const int id = blockIdx.x;
  const int grp = id & 7;                 // XCD group
  const int b = grp >> 1, half = grp & 1;
  const int q0 = (id >> 3) * 128;
  const size_t base = (size_t)b * (4096 * 512);
  const int kvbase = half * 2048;         // element offset of this KV half

  // Q fragments in registers (wave w rows 16w + li); q pre-scaled by QSCALE
  bf16x8 qf[16];
  {
    const __bf16* qp = Q + base + (size_t)(q0 + 16 * w + li) * 512 + 8 * g;
#pragma unroll
    for (int ks = 0; ks < 16; ++ks) qf[ks] = *(const bf16x8*)(qp + ks * 32);
  }

  f32x4 acc[8][4] = {};
  f32x4 lacc = {};
  bf16x8 ones;
#pragma unroll
  for (int j = 0; j < 8; ++j) ones[j] = (__bf16)1.0f;

  auto stageK = [&](int buf, int kt) {
#pragma unroll
    for (int i = 0; i < 8; ++i) {
      int r = w * 8 + i;                       // wave-uniform LDS row
      int y = (lane * 16) ^ ((r & 7) << 4);    // pre-swizzled source byte offset
      gll16(K + base + (size_t)(kvbase + kt * 64 + r) * 512 + (y >> 1),
            &Ks[buf][r][0]);
    }
  };

  // PV for tile ktv whose P sits in Ps[prv]; V read directly from global.
  auto pvblock = [&](int prv, int ktv) {
    const __bf16* vb = VT + (size_t)b * 2097152 + kvbase + ktv * 64;
#pragma unroll
    for (int ks = 0; ks < 2; ++ks) {
      bf16x8 pa[8];
#pragma unroll
      for (int rt = 0; rt < 8; ++rt) {
        int prow = rt * 16 + li;
        int gcol = (ks * 4 + g) ^ (li & 7);
        pa[rt] = *(const bf16x8*)&Ps[prv][prow][gcol * 8];
      }
      lacc = mfma16(pa[w], ones, lacc);
      __builtin_amdgcn_s_setprio(1);
#pragma unroll
      for (int ct = 0; ct < 4; ++ct) {
        bf16x8 vfr = *(const bf16x8*)(vb +
            (size_t)(64 * w + 16 * ct + li) * 4096 + ks * 32 + 8 * g);
#pragma unroll
        for (int rt = 0; rt < 8; ++rt)
          acc[rt][ct] = mfma16(pa[rt], vfr, acc[rt][ct]);
      }
      __builtin_amdgcn_s_setprio(0);
    }
  };

  stageK(0, 0);
  __syncthreads();

  for (int kt = 0; kt < 32; ++kt) {
    const int cur = kt & 1;
    if (kt + 1 < 32) stageK(cur ^ 1, kt + 1);

    // ---- S = Q K^T (wave rows 16w.., kv 0..63 of tile), reads Ks[cur] ----
    __builtin_amdgcn_s_setprio(1);
    f32x4 s[4] = {};
#pragma unroll
    for (int ks = 0; ks < 16; ++ks) {
      int e = (ks * 32 + 8 * g) ^ ((li & 7) * 8);
#pragma unroll
      for (int kvt = 0; kvt < 4; ++kvt) {
        bf16x8 kf = *(const bf16x8*)&Ks[cur][kvt * 16 + li][e];
        s[kvt] = mfma16(qf[ks], kf, s[kvt]);
      }
    }
    __builtin_amdgcn_s_setprio(0);

    // ---- softmax (no max-shift) + Ps[cur] write (s dies here) ----
#pragma unroll
    for (int kvt = 0; kvt < 4; ++kvt) {
#pragma unroll
      for (int e = 0; e < 4; ++e) {
        float p = exp2f(s[kvt][e]);
        int row = 16 * w + 4 * g + e;
        int gcol = (kvt * 2 + (li >> 3)) ^ (row & 7);
        Ps[cur][row][gcol * 8 + (li & 7)] = (__bf16)p;
      }
    }

    // ---- PV(t-1): reads Ps[cur^1] + V(kt-1) from L2 ----
    if (kt > 0) pvblock(cur ^ 1, kt - 1);

    __syncthreads();  // one barrier per kt: staging + Ps visible, reads done
  }
  pvblock(1, 31);  // last tile: Ps[1], V(31)

  // ---- write l-sums + unnormalized partial O ----
  if (li == 0)
    *(f32x4*)(stats + half * 16384 + b * 4096 + q0 + 16 * w + 4 * g) = lacc;
#pragma unroll
  for (int rt = 0; rt < 8; ++rt) {
#pragma unroll
    for (int ct = 0; ct < 4; ++ct) {
      int rr = q0 + rt * 16 + 4 * g;
      int cc = w * 64 + ct * 16 + li;
#pragma unroll
      for (int e = 0; e < 4; ++e)
        Op[(size_t)half * 8388608 + base + (size_t)(rr + e) * 512 + cc] =
            (__bf16)acc[rt][ct][e];
    }
  }
}

// combine the two KV halves: O = (O0 + O1) / (l0 + l1)
__global__ __launch_bounds__(256) void combine2(const __bf16* __restrict__ Op,
                                                const float* __restrict__ stats,
                                                __bf16* __restrict__ ao) {
  int gid = blockIdx.x * 256 + threadIdx.x;
  int row = gid >> 6;
  int c = (gid & 63) * 8;
  float l0 = stats[row], l1 = stats[16384 + row];
  float inv = 1.f / (l0 + l1);
  bf16x8 v0 = *(const bf16x8*)(Op + (size_t)row * 512 + c);
  bf16x8 v1 = *(const bf16x8*)(Op + 8388608 + (size_t)row * 512 + c);
  bf16x8 o;
#pragma unroll
  for (int j = 0; j < 8; ++j)
    o[j] = (__bf16)(((float)v0[j] + (float)v1[j]) * inv);
  *(bf16x8*)(ao + (size_t)row * 512 + c) = o;
}

// ---------------------------------------------------------------------------
extern "C" void kernel_launch(void* const* d_in, const int* in_sizes, int n_in,
                              void* d_out, int out_size, void* d_ws, size_t ws_size,
                              hipStream_t stream) {
  const float* x   = (const float*)d_in[0];
  const float* lnw = (const float*)d_in[1];
  const float* lnb = (const float*)d_in[2];
  const float* wq  = (const float*)d_in[3];
  const float* bq  = (const float*)d_in[4];
  const float* wk  = (const float*)d_in[5];
  const float* bk  = (const float*)d_in[6];
  const float* wv  = (const float*)d_in[7];
  const float* bv  = (const float*)d_in[8];
  const float* wp  = (const float*)d_in[9];
  const float* bp  = (const float*)d_in[10];

  char* ws = (char*)d_ws;
  const size_t MB = 1024 * 1024;
  __bf16* h    = (__bf16*)(ws);                 // 16 MB (reused as attn-out)
  __bf16* q    = (__bf16*)(ws + 16 * MB);       // 16 MB (q at +0, k at +8M elems)
  __bf16* vt   = (__bf16*)(ws + 48 * MB);       // 16 MB (V transposed [b][c][l])
  __bf16* wbf  = (__bf16*)(ws + 64 * MB);       // 2 MB (wq|wk|wv|wp bf16)
  float*  mu   = (float*)(ws + 66 * MB);        // 64 KB
  float*  rsg  = (float*)(ws + 66 * MB + 65536);// 64 KB
  __bf16* op   = (__bf16*)(ws + 67 * MB);       // 32 MB (both halves)
  float*  stats= (float*)(ws + 99 * MB);        // 128 KB (l0,l1)
  __bf16* ao   = h;                             // h dead after QKV GEMM

  cvt_w<<<1024, 256, 0, stream>>>(wq, wk, wv, wp, wbf);
  ln_stats<<<dim3(64, 4), 256, 0, stream>>>(x, mu, rsg);
  ln_apply<<<dim3(64, 8, 4), 256, 0, stream>>>(x, mu, rsg, lnw, lnb, h);
  gemm_qkv<<<1536, 256, 0, stream>>>(h, wbf, bq, bk, bv, q, vt);
  flash_half<<<256, 512, 0, stream>>>(q, q + 8388608, vt, op, stats);
  combine2<<<4096, 256, 0, stream>>>(op, stats, ao);
  gemm_pp<<<512, 256, 0, stream>>>(wbf + 3 * 262144, ao, bp, x,
                                   (float*)d_out);
}

// Round 7
// 341.588 us; speedup vs baseline: 2.9731x; 2.9731x over previous
//
#include <hip/hip_runtime.h>

// ---------------------------------------------------------------------------
// AttnBlock: LN(channel) -> QKV 1x1 conv -> full attention (L=4096, d=512)
//            -> proj -> SELU -> residual.   B=4, C=512, L=4096.  bf16 MFMA.
// Round 7: r4 mechanisms (gll16-staged K AND V, XCD grouping) + KVBLK=64
// with 2 barriers/kt (half the barrier events of r4) via SINGLE-buffered
// Ks/VTs/Ps (144 KB LDS). Lean register schedule (no pa[8] blowup - r6's
// spill lesson). GEMMs keep XCD-chunked swizzles.
// ---------------------------------------------------------------------------

typedef __attribute__((ext_vector_type(8))) __bf16 bf16x8;
typedef __attribute__((ext_vector_type(4))) __bf16 bf16x4;
typedef __attribute__((ext_vector_type(4))) float  f32x4;

__device__ __forceinline__ f32x4 mfma16(bf16x8 a, bf16x8 b, f32x4 c) {
  return __builtin_amdgcn_mfma_f32_16x16x32_bf16(a, b, c, 0, 0, 0);
}

// async global->LDS, 16B per lane; lds dest is wave-uniform base (HW adds lane*16)
__device__ __forceinline__ void gll16(const void* g, void* l) {
  __builtin_amdgcn_global_load_lds(
      (const __attribute__((address_space(1))) unsigned int*)g,
      (__attribute__((address_space(3))) unsigned int*)l, 16, 0, 0);
}

__device__ __forceinline__ float selu_f(float v) {
  return 1.0507009873554805f * (v > 0.f ? v : 1.6732632423543772f * (__expf(v) - 1.f));
}

// log2(e) / sqrt(512): folded into q at the QKV-GEMM epilogue
#define QSCALE ((float)(1.4426950408889634 / 22.627416997969522))

// ---------------------------------------------------------------------------
// weight fp32 -> bf16, 4 matrices packed contiguously [wq;wk;wv;wp]
// ---------------------------------------------------------------------------
__global__ __launch_bounds__(256) void cvt_w(const float* __restrict__ w0,
                                             const float* __restrict__ w1,
                                             const float* __restrict__ w2,
                                             const float* __restrict__ w3,
                                             __bf16* __restrict__ dst) {
  int idx = blockIdx.x * 256 + threadIdx.x;           // 0..262143 (x4 floats)
  int which = idx >> 16;
  const float* s = which == 0 ? w0 : which == 1 ? w1 : which == 2 ? w2 : w3;
  f32x4 v = *(const f32x4*)(s + (size_t)(idx & 65535) * 4);
  bf16x4 o = {(__bf16)v.x, (__bf16)v.y, (__bf16)v.z, (__bf16)v.w};
  *(bf16x4*)(dst + (size_t)idx * 4) = o;
}

// ---------------------------------------------------------------------------
// LayerNorm stats over C for each (b,l): coalesced along l
// ---------------------------------------------------------------------------
__global__ __launch_bounds__(256) void ln_stats(const float* __restrict__ x,
                                                float* __restrict__ mu,
                                                float* __restrict__ rs) {
  __shared__ float shs[4][64], shq[4][64];
  int b = blockIdx.y, l0 = blockIdx.x * 64;
  int i = threadIdx.x & 63, j = threadIdx.x >> 6;
  const float* xp = x + (size_t)b * 512 * 4096 + l0 + i;
  float s = 0.f, sq = 0.f;
  for (int c = j; c < 512; c += 4) {
    float v = xp[(size_t)c * 4096];
    s += v; sq += v * v;
  }
  shs[j][i] = s; shq[j][i] = sq;
  __syncthreads();
  if (threadIdx.x < 64) {
    float S = shs[0][i] + shs[1][i] + shs[2][i] + shs[3][i];
    float Q = shq[0][i] + shq[1][i] + shq[2][i] + shq[3][i];
    float m = S * (1.f / 512.f);
    float var = Q * (1.f / 512.f) - m * m;
    int idx = b * 4096 + l0 + i;
    mu[idx] = m;
    rs[idx] = rsqrtf(var + 1e-5f);
  }
}

// ---------------------------------------------------------------------------
// LN apply + transpose: x[b,c,l] -> h[(b*L+l)][c] bf16, both sides coalesced
// ---------------------------------------------------------------------------
__global__ __launch_bounds__(256) void ln_apply(const float* __restrict__ x,
                                                const float* __restrict__ mu,
                                                const float* __restrict__ rs,
                                                const float* __restrict__ lw,
                                                const float* __restrict__ lb,
                                                __bf16* __restrict__ h) {
  __shared__ float t[64][65];
  int b = blockIdx.z, c0 = blockIdx.y * 64, l0 = blockIdx.x * 64;
  int li = threadIdx.x & 63, r4 = threadIdx.x >> 6;
  const float* xp = x + (size_t)(b * 512 + c0) * 4096 + l0;
#pragma unroll
  for (int rr = 0; rr < 16; ++rr) {
    int cl = rr * 4 + r4;
    t[cl][li] = xp[(size_t)cl * 4096 + li];
  }
  __syncthreads();
  float gw = lw[c0 + li], gb = lb[c0 + li];
#pragma unroll
  for (int rr = 0; rr < 16; ++rr) {
    int lr = rr * 4 + r4;
    int l = l0 + lr;
    float m = mu[b * 4096 + l], r = rs[b * 4096 + l];
    float v = (t[li][lr] - m) * r * gw + gb;
    h[((size_t)b * 4096 + l) * 512 + c0 + li] = (__bf16)v;
  }
}

// ---------------------------------------------------------------------------
// 128x128 bf16 GEMM, C[i][j] = sum_k A[i][k]*W[j][k], K=512, BK=64.
// QKV variant: q scaled by QSCALE; q,k row-major [pos][c]; v transposed
// to vt[b][c][l].  1-D grid, XCD-chunked: m-panels pinned to one XCD.
// ---------------------------------------------------------------------------
__global__ __launch_bounds__(256, 2) void gemm_qkv(
    const __bf16* __restrict__ A, const __bf16* __restrict__ W,
    const float* __restrict__ b0, const float* __restrict__ b1,
    const float* __restrict__ b2, __bf16* __restrict__ out,
    __bf16* __restrict__ vt) {
  __shared__ __align__(16) __bf16 As[128 * 64];
  __shared__ __align__(16) __bf16 Bs[128 * 64];
  const int tid = threadIdx.x;
  const int w = tid >> 6, lane = tid & 63, g = lane >> 4, li = lane & 15;
  // 1536 blocks: xcd = id&7 owns m-tiles [16*xcd, 16*xcd+16) x all 12 n-tiles
  const int id = blockIdx.x;
  const int jj = id >> 3;
  const int m0 = (16 * (id & 7) + jj / 12) * 128;
  const int n0 = (jj % 12) * 128;
  const int wm = w >> 1, wn = w & 1;
  const int srow = lane >> 3;                  // 0..7
  const int scol = ((lane & 7) ^ srow) * 8;    // swizzled source granule (elems)
  f32x4 acc[4][4] = {};
  for (int kt = 0; kt < 8; ++kt) {
    __syncthreads();
#pragma unroll
    for (int qq = 0; qq < 4; ++qq) {
      int r = w * 32 + qq * 8;
      gll16(A + (size_t)(m0 + r + srow) * 512 + kt * 64 + scol, &As[r * 64]);
      gll16(W + (size_t)(n0 + r + srow) * 512 + kt * 64 + scol, &Bs[r * 64]);
    }
    __syncthreads();
#pragma unroll
    for (int kk = 0; kk < 2; ++kk) {
      bf16x8 af[4], bf[4];
#pragma unroll
      for (int t = 0; t < 4; ++t) {
        int ra = wm * 64 + t * 16 + li;
        af[t] = *(const bf16x8*)&As[ra * 64 + ((kk * 32 + 8 * g) ^ ((ra & 7) * 8))];
        int rb = wn * 64 + t * 16 + li;
        bf[t] = *(const bf16x8*)&Bs[rb * 64 + ((kk * 32 + 8 * g) ^ ((rb & 7) * 8))];
      }
#pragma unroll
      for (int i = 0; i < 4; ++i)
#pragma unroll
        for (int j = 0; j < 4; ++j) acc[i][j] = mfma16(af[i], bf[j], acc[i][j]);
    }
  }
  const int which = n0 >> 9;  // 0=q,1=k,2=v (block never crosses a 512 boundary)
  if (which < 2) {
    const float* bb = which == 0 ? b0 : b1;
    const float sc = which == 0 ? QSCALE : 1.0f;
    __bf16* o = out + (size_t)which * 8388608;
#pragma unroll
    for (int i = 0; i < 4; ++i) {
#pragma unroll
      for (int j = 0; j < 4; ++j) {
        int r = m0 + wm * 64 + i * 16 + 4 * g;
        int c = (n0 & 511) + wn * 64 + j * 16 + li;
        float bv = bb[c];
#pragma unroll
        for (int e = 0; e < 4; ++e)
          o[(size_t)(r + e) * 512 + c] = (__bf16)((acc[i][j][e] + bv) * sc);
      }
    }
  } else {
    // transposed write: vt[b][channel][l]
#pragma unroll
    for (int i = 0; i < 4; ++i) {
#pragma unroll
      for (int j = 0; j < 4; ++j) {
        int r = m0 + wm * 64 + i * 16 + 4 * g;   // flat position b*4096+l
        int c = (n0 & 511) + wn * 64 + j * 16 + li;  // channel
        float bv = b2[c];
#pragma unroll
        for (int e = 0; e < 4; ++e) {
          int row = r + e;
          vt[((size_t)(row >> 12) * 512 + c) * 4096 + (row & 4095)] =
              (__bf16)(acc[i][j][e] + bv);
        }
      }
    }
  }
}

// PP variant: C[o][pos] = sum wp[o][k]*ao[pos][k]; epilogue bias+SELU+residual,
// writes out[b][o][l] fp32 fully coalesced (lanes along l).
__global__ __launch_bounds__(256, 2) void gemm_pp(
    const __bf16* __restrict__ A, const __bf16* __restrict__ Bm,
    const float* __restrict__ bias, const float* __restrict__ xres,
    float* __restrict__ out) {
  __shared__ __align__(16) __bf16 As[128 * 64];
  __shared__ __align__(16) __bf16 Bs[128 * 64];
  const int tid = threadIdx.x;
  const int w = tid >> 6, lane = tid & 63, g = lane >> 4, li = lane & 15;
  // 512 blocks: xcd = id&7 owns position-tiles [16*xcd,16*xcd+16) x 4 m-tiles
  const int id = blockIdx.x;
  const int jj = id >> 3;
  const int n0 = (16 * (id & 7) + (jj & 15)) * 128;  // position
  const int m0 = (jj >> 4) * 128;                    // output channel
  const int wm = w >> 1, wn = w & 1;
  const int srow = lane >> 3;
  const int scol = ((lane & 7) ^ srow) * 8;
  f32x4 acc[4][4] = {};
  for (int kt = 0; kt < 8; ++kt) {
    __syncthreads();
#pragma unroll
    for (int qq = 0; qq < 4; ++qq) {
      int r = w * 32 + qq * 8;
      gll16(A + (size_t)(m0 + r + srow) * 512 + kt * 64 + scol, &As[r * 64]);
      gll16(Bm + (size_t)(n0 + r + srow) * 512 + kt * 64 + scol, &Bs[r * 64]);
    }
    __syncthreads();
#pragma unroll
    for (int kk = 0; kk < 2; ++kk) {
      bf16x8 af[4], bf[4];
#pragma unroll
      for (int t = 0; t < 4; ++t) {
        int ra = wm * 64 + t * 16 + li;
        af[t] = *(const bf16x8*)&As[ra * 64 + ((kk * 32 + 8 * g) ^ ((ra & 7) * 8))];
        int rb = wn * 64 + t * 16 + li;
        bf[t] = *(const bf16x8*)&Bs[rb * 64 + ((kk * 32 + 8 * g) ^ ((rb & 7) * 8))];
      }
#pragma unroll
      for (int i = 0; i < 4; ++i)
#pragma unroll
        for (int j = 0; j < 4; ++j) acc[i][j] = mfma16(af[i], bf[j], acc[i][j]);
    }
  }
#pragma unroll
  for (int i = 0; i < 4; ++i) {
#pragma unroll
    for (int j = 0; j < 4; ++j) {
      int r = m0 + wm * 64 + i * 16 + 4 * g;   // output channel o
      int c = n0 + wn * 64 + j * 16 + li;      // flat position b*4096+l
      int bb = c >> 12, l = c & 4095;
#pragma unroll
      for (int e = 0; e < 4; ++e) {
        float v = acc[i][j][e] + bias[r + e];
        size_t oi = ((size_t)bb * 512 + (r + e)) * 4096 + l;
        out[oi] = xres[oi] + selu_f(v);
      }
    }
  }
}

// ---------------------------------------------------------------------------
// Flash attention, one block = 128 q-rows x one half (2048) of the KV range.
// Grid 256 blocks: group = id&7 = b*2+half pinned per-XCD (K/V L2-resident).
// 8 waves: wave w owns S rows 16w..16w+15 and O cols 64w..64w+63.
// KVBLK=64, 32 iters, 2 barriers each (half of r4's barrier events).
// SINGLE-buffered Ks[64][512] + VTs[512][64] + Ps[128][64] = 144 KB:
//   [top] (VTs for kt staged last iter) QKT(kt)+SM->Ps | bar#1 |
//   stageK(kt+1), PV(kt) | bar#2 | stageVT(kt+1)  -> hazard-free.
// Softmax: no max-shift (exp2 of pre-scaled scores); l via ones-MFMA;
// O unnormalized, normalized in combine2.
// ---------------------------------------------------------------------------
__global__ __launch_bounds__(512, 2) void flash_half(
    const __bf16* __restrict__ Q, const __bf16* __restrict__ K,
    const __bf16* __restrict__ VT, __bf16* __restrict__ Op,
    float* __restrict__ stats) {
  __shared__ __align__(16) __bf16 Ks[64][512];    // 64 KB
  __shared__ __align__(16) __bf16 VTs[512][64];   // 64 KB
  __shared__ __align__(16) __bf16 Ps[128][64];    // 16 KB

  const int tid = threadIdx.x;
  const int w = tid >> 6, lane = tid & 63, g = lane >> 4, li = lane & 15;
  const int id = blockIdx.x;
  const int grp = id & 7;                 // XCD group
  const int b = grp >> 1, half = grp & 1;
  const int q0 = (id >> 3) * 128;
  const size_t base = (size_t)b * (4096 * 512);
  const int kvbase = half * 2048;         // element offset of this KV half

  // Q fragments in registers (wave w rows 16w + li); q pre-scaled by QSCALE
  bf16x8 qf[16];
  {
    const __bf16* qp = Q + base + (size_t)(q0 + 16 * w + li) * 512 + 8 * g;
#pragma unroll
    for (int ks = 0; ks < 16; ++ks) qf[ks] = *(const bf16x8*)(qp + ks * 32);
  }

  f32x4 acc[8][4] = {};
  f32x4 lacc = {};
  bf16x8 ones;
#pragma unroll
  for (int j = 0; j < 8; ++j) ones[j] = (__bf16)1.0f;

  auto stageK = [&](int kt) {
#pragma unroll
    for (int i = 0; i < 8; ++i) {
      int r = w * 8 + i;                       // wave-uniform LDS row
      int y = (lane * 16) ^ ((r & 7) << 4);    // pre-swizzled source byte offset
      gll16(K + base + (size_t)(kvbase + kt * 64 + r) * 512 + (y >> 1),
            &Ks[r][0]);
    }
  };
  // VTs[d][64 kv] rows of 128B = 8 granules; slot s of row d holds source
  // granule s ^ (d&7).  Per gll16: 8 rows x 8 slots; lane -> row d0+(lane>>3),
  // slot lane&7, source granule (lane&7)^(lane>>3).
  auto stageVT = [&](int kt) {
    const int drow = lane >> 3;
    const int gr = (lane & 7) ^ drow;
#pragma unroll
    for (int i = 0; i < 8; ++i) {
      int d0 = w * 64 + i * 8;                 // wave-uniform LDS row block
      gll16(VT + (size_t)b * 2097152 + (size_t)(d0 + drow) * 4096 +
                kvbase + kt * 64 + gr * 8,
            &VTs[d0][0]);
    }
  };

  stageK(0);
  stageVT(0);
  __syncthreads();

  for (int kt = 0; kt < 32; ++kt) {
    // ---- S = Q K^T (wave rows 16w.., kv 0..63 of tile), reads Ks ----
    __builtin_amdgcn_s_setprio(1);
    f32x4 s[4] = {};
#pragma unroll
    for (int ks = 0; ks < 16; ++ks) {
      int e = (ks * 32 + 8 * g) ^ ((li & 7) * 8);
#pragma unroll
      for (int kvt = 0; kvt < 4; ++kvt) {
        bf16x8 kf = *(const bf16x8*)&Ks[kvt * 16 + li][e];
        s[kvt] = mfma16(qf[ks], kf, s[kvt]);
      }
    }
    __builtin_amdgcn_s_setprio(0);

    // ---- softmax (no max-shift) + Ps write; s dies here ----
#pragma unroll
    for (int kvt = 0; kvt < 4; ++kvt) {
#pragma unroll
      for (int e = 0; e < 4; ++e) {
        float p = exp2f(s[kvt][e]);
        int row = 16 * w + 4 * g + e;
        int slot = (2 * kvt + (li >> 3)) ^ (row & 7);
        Ps[row][slot * 8 + (li & 7)] = (__bf16)p;
      }
    }
    __syncthreads();  // bar#1: Ps visible; QKT done with Ks; VTs(kt) drained

    if (kt + 1 < 32) stageK(kt + 1);  // overwrite Ks; drains at bar#2

    // ---- PV(kt): bfr from VTs, af from Ps (lean: bfr[4] + one af) ----
#pragma unroll
    for (int ks = 0; ks < 2; ++ks) {
      bf16x8 bfr[4];
#pragma unroll
      for (int ct = 0; ct < 4; ++ct) {
        int dcol = 64 * w + 16 * ct + li;
        int slot = (4 * ks + g) ^ (li & 7);
        bfr[ct] = *(const bf16x8*)&VTs[dcol][slot * 8];
      }
      __builtin_amdgcn_s_setprio(1);
#pragma unroll
      for (int rt = 0; rt < 8; ++rt) {
        int prow = rt * 16 + li;
        int slot = (4 * ks + g) ^ (li & 7);
        bf16x8 af = *(const bf16x8*)&Ps[prow][slot * 8];
        if (rt == w) lacc = mfma16(af, ones, lacc);
#pragma unroll
        for (int ct = 0; ct < 4; ++ct)
          acc[rt][ct] = mfma16(af, bfr[ct], acc[rt][ct]);
      }
      __builtin_amdgcn_s_setprio(0);
    }
    __syncthreads();  // bar#2: PV done with VTs/Ps; stageK drained

    if (kt + 1 < 32) stageVT(kt + 1);  // overwrite VTs; drains at next bar#1
  }

  // ---- write l-sums + unnormalized partial O ----
  if (li == 0)
    *(f32x4*)(stats + half * 16384 + b * 4096 + q0 + 16 * w + 4 * g) = lacc;
#pragma unroll
  for (int rt = 0; rt < 8; ++rt) {
#pragma unroll
    for (int ct = 0; ct < 4; ++ct) {
      int rr = q0 + rt * 16 + 4 * g;
      int cc = w * 64 + ct * 16 + li;
#pragma unroll
      for (int e = 0; e < 4; ++e)
        Op[(size_t)half * 8388608 + base + (size_t)(rr + e) * 512 + cc] =
            (__bf16)acc[rt][ct][e];
    }
  }
}

// combine the two KV halves: O = (O0 + O1) / (l0 + l1)
__global__ __launch_bounds__(256) void combine2(const __bf16* __restrict__ Op,
                                                const float* __restrict__ stats,
                                                __bf16* __restrict__ ao) {
  int gid = blockIdx.x * 256 + threadIdx.x;
  int row = gid >> 6;
  int c = (gid & 63) * 8;
  float l0 = stats[row], l1 = stats[16384 + row];
  float inv = 1.f / (l0 + l1);
  bf16x8 v0 = *(const bf16x8*)(Op + (size_t)row * 512 + c);
  bf16x8 v1 = *(const bf16x8*)(Op + 8388608 + (size_t)row * 512 + c);
  bf16x8 o;
#pragma unroll
  for (int j = 0; j < 8; ++j)
    o[j] = (__bf16)(((float)v0[j] + (float)v1[j]) * inv);
  *(bf16x8*)(ao + (size_t)row * 512 + c) = o;
}

// ---------------------------------------------------------------------------
extern "C" void kernel_launch(void* const* d_in, const int* in_sizes, int n_in,
                              void* d_out, int out_size, void* d_ws, size_t ws_size,
                              hipStream_t stream) {
  const float* x   = (const float*)d_in[0];
  const float* lnw = (const float*)d_in[1];
  const float* lnb = (const float*)d_in[2];
  const float* wq  = (const float*)d_in[3];
  const float* bq  = (const float*)d_in[4];
  const float* wk  = (const float*)d_in[5];
  const float* bk  = (const float*)d_in[6];
  const float* wv  = (const float*)d_in[7];
  const float* bv  = (const float*)d_in[8];
  const float* wp  = (const float*)d_in[9];
  const float* bp  = (const float*)d_in[10];

  char* ws = (char*)d_ws;
  const size_t MB = 1024 * 1024;
  __bf16* h    = (__bf16*)(ws);                 // 16 MB (reused as attn-out)
  __bf16* q    = (__bf16*)(ws + 16 * MB);       // 16 MB (q at +0, k at +8M elems)
  __bf16* vt   = (__bf16*)(ws + 48 * MB);       // 16 MB (V transposed [b][c][l])
  __bf16* wbf  = (__bf16*)(ws + 64 * MB);       // 2 MB (wq|wk|wv|wp bf16)
  float*  mu   = (float*)(ws + 66 * MB);        // 64 KB
  float*  rsg  = (float*)(ws + 66 * MB + 65536);// 64 KB
  __bf16* op   = (__bf16*)(ws + 67 * MB);       // 32 MB (both halves)
  float*  stats= (float*)(ws + 99 * MB);        // 128 KB (l0,l1)
  __bf16* ao   = h;                             // h dead after QKV GEMM

  cvt_w<<<1024, 256, 0, stream>>>(wq, wk, wv, wp, wbf);
  ln_stats<<<dim3(64, 4), 256, 0, stream>>>(x, mu, rsg);
  ln_apply<<<dim3(64, 8, 4), 256, 0, stream>>>(x, mu, rsg, lnw, lnb, h);
  gemm_qkv<<<1536, 256, 0, stream>>>(h, wbf, bq, bk, bv, q, vt);
  flash_half<<<256, 512, 0, stream>>>(q, q + 8388608, vt, op, stats);
  combine2<<<4096, 256, 0, stream>>>(op, stats, ao);
  gemm_pp<<<512, 256, 0, stream>>>(wbf + 3 * 262144, ao, bp, x,
                                   (float*)d_out);
}